// Round 1
// baseline (547.080 us; speedup 1.0000x reference)
//
#include <hip/hip_runtime.h>
#include <hip/hip_bf16.h>

// B=2, T=2048, C=2048, H=16, HD=128
#define B_  2
#define T_  2048
#define C_  2048
#define H_  16
#define HD_ 128

using bf16x8 = __attribute__((ext_vector_type(8))) __bf16;
using f32x4  = __attribute__((ext_vector_type(4))) float;

__device__ __forceinline__ unsigned short f2bs(float f) {
    __hip_bfloat16 h = __float2bfloat16(f);
    return __builtin_bit_cast(unsigned short, h);
}

// ---------------- convert fp32 -> bf16 (vectorized) ----------------
__global__ void k_f2b(const float* __restrict__ in, unsigned short* __restrict__ out, int n4) {
    int i = blockIdx.x * blockDim.x + threadIdx.x;
    if (i < n4) {
        float4 v = reinterpret_cast<const float4*>(in)[i];
        ushort4 o;
        o.x = f2bs(v.x); o.y = f2bs(v.y); o.z = f2bs(v.z); o.w = f2bs(v.w);
        reinterpret_cast<ushort4*>(out)[i] = o;
    }
}

// ---------------- transpose + convert: in [K][N] fp32 -> out [N][K] bf16 ----------------
__global__ __launch_bounds__(256) void k_transpose_f2b(const float* __restrict__ in,
                                                       unsigned short* __restrict__ out,
                                                       int K, int N) {
    __shared__ unsigned short t[64][65];
    int k0 = blockIdx.y * 64, n0 = blockIdx.x * 64;
    int tid = threadIdx.x;
#pragma unroll
    for (int p = 0; p < 4; ++p) {
        int idx = p * 256 + tid;
        int r = idx >> 4, c = (idx & 15) << 2;
        float4 v = *reinterpret_cast<const float4*>(in + (long)(k0 + r) * N + n0 + c);
        t[r][c] = f2bs(v.x); t[r][c + 1] = f2bs(v.y);
        t[r][c + 2] = f2bs(v.z); t[r][c + 3] = f2bs(v.w);
    }
    __syncthreads();
#pragma unroll
    for (int p = 0; p < 4; ++p) {
        int idx = p * 256 + tid;
        int r = idx >> 4, c = (idx & 15) << 2;
        ushort4 o;
        o.x = t[c][r]; o.y = t[c + 1][r]; o.z = t[c + 2][r]; o.w = t[c + 3][r];
        *reinterpret_cast<ushort4*>(out + (long)(n0 + r) * K + k0 + c) = o;
    }
}

// ---------------- GEMM: A[M][K] bf16 x Bt[N][K] bf16 -> epilogue per MODE ----------------
// MODE 0: write qkv scatter [3][B*H][T][HD] bf16.  MODE 1: out fp32 [M][N] + bias.
template <int MODE>
__global__ __launch_bounds__(256, 2) void k_gemm(const unsigned short* __restrict__ A,
                                                 const unsigned short* __restrict__ Bt,
                                                 int M, int N, int K,
                                                 unsigned short* __restrict__ qkv,
                                                 float* __restrict__ out,
                                                 const float* __restrict__ bias) {
    __shared__ __align__(16) unsigned short lA[128 * 40];  // stride 40 (+8 pad): 2-way banks
    __shared__ __align__(16) unsigned short lB[128 * 40];

    int tid = threadIdx.x;
    int wave = tid >> 6, lane = tid & 63;
    int quad = lane >> 4, l16 = lane & 15;
    int wr = (wave >> 1) * 64, wc = (wave & 1) * 64;
    int m0 = blockIdx.y * 128, n0 = blockIdx.x * 128;

    int sr = tid >> 2;        // 0..63
    int sc = (tid & 3) << 3;  // 0,8,16,24

    f32x4 zero = {0.f, 0.f, 0.f, 0.f};
    f32x4 acc[4][4];
#pragma unroll
    for (int i = 0; i < 4; ++i)
#pragma unroll
        for (int j = 0; j < 4; ++j) acc[i][j] = zero;

    for (int k0 = 0; k0 < K; k0 += 32) {
        __syncthreads();
#pragma unroll
        for (int p = 0; p < 2; ++p) {
            int r = sr + p * 64;
            *reinterpret_cast<int4*>(&lA[r * 40 + sc]) =
                *reinterpret_cast<const int4*>(A + (long)(m0 + r) * K + k0 + sc);
            *reinterpret_cast<int4*>(&lB[r * 40 + sc]) =
                *reinterpret_cast<const int4*>(Bt + (long)(n0 + r) * K + k0 + sc);
        }
        __syncthreads();
        bf16x8 af[4], bfr[4];
#pragma unroll
        for (int i = 0; i < 4; ++i)
            af[i] = *reinterpret_cast<const bf16x8*>(&lA[(wr + i * 16 + l16) * 40 + quad * 8]);
#pragma unroll
        for (int j = 0; j < 4; ++j)
            bfr[j] = *reinterpret_cast<const bf16x8*>(&lB[(wc + j * 16 + l16) * 40 + quad * 8]);
#pragma unroll
        for (int i = 0; i < 4; ++i)
#pragma unroll
            for (int j = 0; j < 4; ++j)
                acc[i][j] = __builtin_amdgcn_mfma_f32_16x16x32_bf16(af[i], bfr[j], acc[i][j], 0, 0, 0);
    }

#pragma unroll
    for (int i = 0; i < 4; ++i) {
#pragma unroll
        for (int j = 0; j < 4; ++j) {
#pragma unroll
            for (int r = 0; r < 4; ++r) {
                int m = m0 + wr + i * 16 + quad * 4 + r;
                int n = n0 + wc + j * 16 + l16;
                float v = acc[i][j][r];
                if (MODE == 0) {
                    int s = n >> 11, col = n & 2047;
                    int h = col >> 7, hd = col & 127;
                    int b = m >> 11, t = m & 2047;
                    qkv[(long)s * (B_ * H_ * T_ * HD_) +
                        ((long)(b * H_ + h) * T_ + t) * HD_ + hd] = f2bs(v);
                } else {
                    out[(long)m * N + n] = v + bias[n];
                }
            }
        }
    }
}

// ---------------- flash attention: qkv [3][B*H][T][HD] bf16 -> y [B*T][C] bf16 ----------------
__global__ __launch_bounds__(256, 2) void k_attn(const unsigned short* __restrict__ qkv,
                                                 unsigned short* __restrict__ y) {
    __shared__ __align__(16) unsigned short lK[32 * 136];    // [key][hd], stride 136
    __shared__ __align__(16) unsigned short lVt[128 * 40];   // [hd][key], stride 40
    __shared__ __align__(16) unsigned short lP[4][16 * 40];  // per-wave P, stride 40

    int tid = threadIdx.x;
    int wave = tid >> 6, lane = tid & 63;
    int quad = lane >> 4, l16 = lane & 15;
    int bh = blockIdx.y;        // 0..31
    int qb = blockIdx.x * 64;   // q-tile base

    const unsigned short* Qh = qkv + (long)bh * (T_ * HD_);
    const unsigned short* Kh = qkv + (long)(B_ * H_) * T_ * HD_ + (long)bh * (T_ * HD_);
    const unsigned short* Vh = qkv + 2L * (B_ * H_) * T_ * HD_ + (long)bh * (T_ * HD_);

    // preload this wave's 16 Q rows as A-fragments (A[m=l16][k=quad*8+j], 4 k-steps)
    bf16x8 aQ[4];
    int qrow = qb + wave * 16 + l16;
#pragma unroll
    for (int kk = 0; kk < 4; ++kk)
        aQ[kk] = *reinterpret_cast<const bf16x8*>(Qh + (long)qrow * HD_ + kk * 32 + quad * 8);

    float m_s[4], l_s[4];
    f32x4 O[8];
    f32x4 zero = {0.f, 0.f, 0.f, 0.f};
#pragma unroll
    for (int r = 0; r < 4; ++r) { m_s[r] = -1e30f; l_s[r] = 0.f; }
#pragma unroll
    for (int h = 0; h < 8; ++h) O[h] = zero;

    int qmax = qb + wave * 16 + 15;
    const float scl = 0.08838834764831845f;  // 1/sqrt(128)

    int rk = tid >> 4;            // 0..15
    int ck = (tid & 15) << 3;     // 0..120
    int rv = tid & 31;            // 0..31
    int cv = (tid >> 5) << 3;     // 0..56

    for (int kb = 0; kb < qb + 64; kb += 32) {
        __syncthreads();
        // stage K tile [32][128] -> lK (row-major, padded)
#pragma unroll
        for (int p = 0; p < 2; ++p)
            *reinterpret_cast<int4*>(&lK[(rk + p * 16) * 136 + ck]) =
                *reinterpret_cast<const int4*>(Kh + (long)(kb + rk + p * 16) * HD_ + ck);
        // stage V tile transposed -> lVt[hd][key]
#pragma unroll
        for (int p = 0; p < 2; ++p) {
            int cbase = cv + p * 64;
            ushort4 v0 = *reinterpret_cast<const ushort4*>(Vh + (long)(kb + rv) * HD_ + cbase);
            ushort4 v1 = *reinterpret_cast<const ushort4*>(Vh + (long)(kb + rv) * HD_ + cbase + 4);
            lVt[(cbase + 0) * 40 + rv] = v0.x; lVt[(cbase + 1) * 40 + rv] = v0.y;
            lVt[(cbase + 2) * 40 + rv] = v0.z; lVt[(cbase + 3) * 40 + rv] = v0.w;
            lVt[(cbase + 4) * 40 + rv] = v1.x; lVt[(cbase + 5) * 40 + rv] = v1.y;
            lVt[(cbase + 6) * 40 + rv] = v1.z; lVt[(cbase + 7) * 40 + rv] = v1.w;
        }
        __syncthreads();
        if (kb > qmax) continue;  // wave-uniform skip; barriers stay at loop top

        // S = Q K^T for 2 key-subtiles of 16
        f32x4 s0 = zero, s1 = zero;
#pragma unroll
        for (int kk = 0; kk < 4; ++kk) {
            bf16x8 b0 = *reinterpret_cast<const bf16x8*>(&lK[l16 * 136 + kk * 32 + quad * 8]);
            bf16x8 b1 = *reinterpret_cast<const bf16x8*>(&lK[(16 + l16) * 136 + kk * 32 + quad * 8]);
            s0 = __builtin_amdgcn_mfma_f32_16x16x32_bf16(aQ[kk], b0, s0, 0, 0, 0);
            s1 = __builtin_amdgcn_mfma_f32_16x16x32_bf16(aQ[kk], b1, s1, 0, 0, 0);
        }

        // online softmax per row (rows quad*4+r; cols = l16 across 16 lanes)
        int qg = qb + wave * 16 + quad * 4;
#pragma unroll
        for (int r = 0; r < 4; ++r) {
            int q = qg + r;
            float x0 = (kb + l16 <= q) ? s0[r] * scl : -1e30f;
            float x1 = (kb + 16 + l16 <= q) ? s1[r] * scl : -1e30f;
            float mx = fmaxf(x0, x1);
#pragma unroll
            for (int off = 1; off < 16; off <<= 1) mx = fmaxf(mx, __shfl_xor(mx, off));
            float mn = fmaxf(m_s[r], mx);
            float al = __expf(m_s[r] - mn);
            float p0 = __expf(x0 - mn);
            float p1 = __expf(x1 - mn);
            float rs = p0 + p1;
#pragma unroll
            for (int off = 1; off < 16; off <<= 1) rs += __shfl_xor(rs, off);
            m_s[r] = mn;
            l_s[r] = l_s[r] * al + rs;
            lP[wave][(quad * 4 + r) * 40 + l16] = f2bs(p0);
            lP[wave][(quad * 4 + r) * 40 + 16 + l16] = f2bs(p1);
#pragma unroll
            for (int h = 0; h < 8; ++h) O[h][r] *= al;
        }

        // P (A-layout) @ V -> O accumulate over 8 hd-tiles
        bf16x8 pf = *reinterpret_cast<const bf16x8*>(&lP[wave][l16 * 40 + quad * 8]);
#pragma unroll
        for (int h = 0; h < 8; ++h) {
            bf16x8 vf = *reinterpret_cast<const bf16x8*>(&lVt[(h * 16 + l16) * 40 + quad * 8]);
            O[h] = __builtin_amdgcn_mfma_f32_16x16x32_bf16(pf, vf, O[h], 0, 0, 0);
        }
    }

    // write y[b*T+t][h*128 + hd] bf16
    int b = bh >> 4, hh = bh & 15;
#pragma unroll
    for (int r = 0; r < 4; ++r) {
        int t = qb + wave * 16 + quad * 4 + r;
        float inv = 1.f / l_s[r];
#pragma unroll
        for (int h = 0; h < 8; ++h)
            y[(long)(b * T_ + t) * C_ + hh * HD_ + h * 16 + l16] = f2bs(O[h][r] * inv);
    }
}

extern "C" void kernel_launch(void* const* d_in, const int* in_sizes, int n_in,
                              void* d_out, int out_size, void* d_ws, size_t ws_size,
                              hipStream_t stream) {
    const float* x     = (const float*)d_in[0];
    // d_in[1] = causal mask, ignored (handled analytically)
    const float* Wqkv  = (const float*)d_in[2];
    const float* Wproj = (const float*)d_in[3];
    const float* bproj = (const float*)d_in[4];
    float* out = (float*)d_out;

    // workspace layout (bf16 elements); y aliases XB (XB dead after gemm1)
    unsigned short* XB     = (unsigned short*)d_ws;   // [4096][2048]  (later: y)
    unsigned short* WQKVT  = XB + 8388608;            // [6144][2048]
    unsigned short* WPROJT = WQKVT + 12582912;        // [2048][2048]
    unsigned short* QKV    = WPROJT + 4194304;        // [3][32][2048][128]
    if (ws_size < 100663296) return;                  // 96 MB needed

    k_f2b<<<8192, 256, 0, stream>>>(x, XB, 8388608 / 4);
    k_transpose_f2b<<<dim3(6144 / 64, 2048 / 64), 256, 0, stream>>>(Wqkv, WQKVT, 2048, 6144);
    k_transpose_f2b<<<dim3(2048 / 64, 2048 / 64), 256, 0, stream>>>(Wproj, WPROJT, 2048, 2048);
    k_gemm<0><<<dim3(6144 / 128, 4096 / 128), 256, 0, stream>>>(XB, WQKVT, 4096, 6144, 2048,
                                                                QKV, nullptr, nullptr);
    k_attn<<<dim3(2048 / 64, 32), 256, 0, stream>>>(QKV, XB);
    k_gemm<1><<<dim3(2048 / 128, 4096 / 128), 256, 0, stream>>>(XB, WPROJT, 4096, 2048, 2048,
                                                                nullptr, out, bproj);
}

// Round 2
// 437.273 us; speedup vs baseline: 1.2511x; 1.2511x over previous
//
#include <hip/hip_runtime.h>
#include <hip/hip_bf16.h>

// B=2, T=2048, C=2048, H=16, HD=128
#define B_  2
#define T_  2048
#define C_  2048
#define H_  16
#define HD_ 128

using bf16x8 = __attribute__((ext_vector_type(8))) __bf16;
using f32x4  = __attribute__((ext_vector_type(4))) float;

__device__ __forceinline__ unsigned short f2bs(float f) {
    __hip_bfloat16 h = __float2bfloat16(f);
    return __builtin_bit_cast(unsigned short, h);
}

// ---------------- convert fp32 -> bf16 (vectorized) ----------------
__global__ void k_f2b(const float* __restrict__ in, unsigned short* __restrict__ out, int n4) {
    int i = blockIdx.x * blockDim.x + threadIdx.x;
    if (i < n4) {
        float4 v = reinterpret_cast<const float4*>(in)[i];
        ushort4 o;
        o.x = f2bs(v.x); o.y = f2bs(v.y); o.z = f2bs(v.z); o.w = f2bs(v.w);
        reinterpret_cast<ushort4*>(out)[i] = o;
    }
}

// ---------------- transpose + convert: in [K][N] fp32 -> out [N][K] bf16 ----------------
__global__ __launch_bounds__(256) void k_transpose_f2b(const float* __restrict__ in,
                                                       unsigned short* __restrict__ out,
                                                       int K, int N) {
    __shared__ unsigned short t[64][65];
    int k0 = blockIdx.y * 64, n0 = blockIdx.x * 64;
    int tid = threadIdx.x;
#pragma unroll
    for (int p = 0; p < 4; ++p) {
        int idx = p * 256 + tid;
        int r = idx >> 4, c = (idx & 15) << 2;
        float4 v = *reinterpret_cast<const float4*>(in + (long)(k0 + r) * N + n0 + c);
        t[r][c] = f2bs(v.x); t[r][c + 1] = f2bs(v.y);
        t[r][c + 2] = f2bs(v.z); t[r][c + 3] = f2bs(v.w);
    }
    __syncthreads();
#pragma unroll
    for (int p = 0; p < 4; ++p) {
        int idx = p * 256 + tid;
        int r = idx >> 4, c = (idx & 15) << 2;
        ushort4 o;
        o.x = t[c][r]; o.y = t[c + 1][r]; o.z = t[c + 2][r]; o.w = t[c + 3][r];
        *reinterpret_cast<ushort4*>(out + (long)(n0 + r) * K + k0 + c) = o;
    }
}

// ---------------- GEMM: A[M][K] bf16 x Bt[N][K] bf16 -> epilogue per MODE ----------------
// MODE 0: write qkv, Q/K as [bh][T][HD], V transposed as [bh][HD][T].
// MODE 1: out fp32 [M][N] + bias.
template <int MODE>
__global__ __launch_bounds__(256, 2) void k_gemm(const unsigned short* __restrict__ A,
                                                 const unsigned short* __restrict__ Bt,
                                                 int M, int N, int K,
                                                 unsigned short* __restrict__ qkv,
                                                 float* __restrict__ out,
                                                 const float* __restrict__ bias) {
    __shared__ __align__(16) unsigned short lA[128 * 40];  // stride 40 (+8 pad)
    __shared__ __align__(16) unsigned short lB[128 * 40];

    int tid = threadIdx.x;
    int wave = tid >> 6, lane = tid & 63;
    int quad = lane >> 4, l16 = lane & 15;
    int wr = (wave >> 1) * 64, wc = (wave & 1) * 64;
    int m0 = blockIdx.y * 128, n0 = blockIdx.x * 128;

    int sr = tid >> 2;        // 0..63
    int sc = (tid & 3) << 3;  // 0,8,16,24

    f32x4 zero = {0.f, 0.f, 0.f, 0.f};
    f32x4 acc[4][4];
#pragma unroll
    for (int i = 0; i < 4; ++i)
#pragma unroll
        for (int j = 0; j < 4; ++j) acc[i][j] = zero;

    for (int k0 = 0; k0 < K; k0 += 32) {
        __syncthreads();
#pragma unroll
        for (int p = 0; p < 2; ++p) {
            int r = sr + p * 64;
            *reinterpret_cast<int4*>(&lA[r * 40 + sc]) =
                *reinterpret_cast<const int4*>(A + (long)(m0 + r) * K + k0 + sc);
            *reinterpret_cast<int4*>(&lB[r * 40 + sc]) =
                *reinterpret_cast<const int4*>(Bt + (long)(n0 + r) * K + k0 + sc);
        }
        __syncthreads();
        bf16x8 af[4], bfr[4];
#pragma unroll
        for (int i = 0; i < 4; ++i)
            af[i] = *reinterpret_cast<const bf16x8*>(&lA[(wr + i * 16 + l16) * 40 + quad * 8]);
#pragma unroll
        for (int j = 0; j < 4; ++j)
            bfr[j] = *reinterpret_cast<const bf16x8*>(&lB[(wc + j * 16 + l16) * 40 + quad * 8]);
#pragma unroll
        for (int i = 0; i < 4; ++i)
#pragma unroll
            for (int j = 0; j < 4; ++j)
                acc[i][j] = __builtin_amdgcn_mfma_f32_16x16x32_bf16(af[i], bfr[j], acc[i][j], 0, 0, 0);
    }

#pragma unroll
    for (int i = 0; i < 4; ++i) {
#pragma unroll
        for (int j = 0; j < 4; ++j) {
#pragma unroll
            for (int r = 0; r < 4; ++r) {
                int m = m0 + wr + i * 16 + quad * 4 + r;
                int n = n0 + wc + j * 16 + l16;
                float v = acc[i][j][r];
                if (MODE == 0) {
                    int s = n >> 11, col = n & 2047;
                    int h = col >> 7, hd = col & 127;
                    int b = m >> 11, t = m & 2047;
                    long base = (long)s * (B_ * H_ * T_ * HD_);
                    if (s == 2)  // V stored transposed: [bh][HD][T]
                        qkv[base + ((long)(b * H_ + h) * HD_ + hd) * T_ + t] = f2bs(v);
                    else
                        qkv[base + ((long)(b * H_ + h) * T_ + t) * HD_ + hd] = f2bs(v);
                } else {
                    out[(long)m * N + n] = v + bias[n];
                }
            }
        }
    }
}

// ---------------- flash attention ----------------
// qkv: Q,K [bh][T][HD], V [bh][HD][T] (pre-transposed), all bf16 -> y [B*T][C] bf16
// block: 4 waves, 64 q-rows (16/wave), kv-step 64. Grid (bh=32, qtile=32), longest-first.
__global__ __launch_bounds__(256, 3) void k_attn(const unsigned short* __restrict__ qkv,
                                                 unsigned short* __restrict__ y) {
    __shared__ __align__(16) unsigned short lK[64 * 136];    // [key][hd], stride 136
    __shared__ __align__(16) unsigned short lVt[128 * 72];   // [hd][key], stride 72
    __shared__ __align__(16) unsigned short lP[4][16 * 72];  // per-wave P [qrow][key]

    int tid = threadIdx.x;
    int wave = tid >> 6, lane = tid & 63;
    int quad = lane >> 4, l16 = lane & 15;
    int bh = blockIdx.x;                          // 0..31
    int qb = ((int)gridDim.y - 1 - (int)blockIdx.y) * 64;  // heavy tiles dispatch first

    const unsigned short* Qh = qkv + (long)bh * (T_ * HD_);
    const unsigned short* Kh = qkv + (long)(B_ * H_) * T_ * HD_ + (long)bh * (T_ * HD_);
    const unsigned short* Vt = qkv + 2L * (B_ * H_) * T_ * HD_ + (long)bh * (HD_ * T_);

    // preload this wave's 16 Q rows as A-fragments (A[m=l16][k=quad*8+j], 4 k-steps)
    bf16x8 aQ[4];
    int qrow = qb + wave * 16 + l16;
#pragma unroll
    for (int kk = 0; kk < 4; ++kk)
        aQ[kk] = *reinterpret_cast<const bf16x8*>(Qh + (long)qrow * HD_ + kk * 32 + quad * 8);

    float m_s[4], l_s[4];
    f32x4 O[8];
    f32x4 zero = {0.f, 0.f, 0.f, 0.f};
#pragma unroll
    for (int r = 0; r < 4; ++r) { m_s[r] = -1e30f; l_s[r] = 0.f; }
#pragma unroll
    for (int h = 0; h < 8; ++h) O[h] = zero;

    int qmax = qb + wave * 16 + 15;
    const float scl = 0.08838834764831845f;  // 1/sqrt(128)

    for (int kb = 0; kb < qb + 64; kb += 64) {
        __syncthreads();
        // stage K tile [64 keys][128 hd] -> lK (coalesced int4, b128 LDS writes)
#pragma unroll
        for (int p = 0; p < 4; ++p) {
            int id = p * 256 + tid;
            int r = id >> 4, cc = (id & 15) << 3;
            *reinterpret_cast<int4*>(&lK[r * 136 + cc]) =
                *reinterpret_cast<const int4*>(Kh + (long)(kb + r) * HD_ + cc);
        }
        // stage Vt tile [128 hd][64 keys] -> lVt (already transposed in global)
#pragma unroll
        for (int p = 0; p < 4; ++p) {
            int id = p * 256 + tid;
            int r = id >> 3, cc = (id & 7) << 3;
            *reinterpret_cast<int4*>(&lVt[r * 72 + cc]) =
                *reinterpret_cast<const int4*>(Vt + (long)r * T_ + kb + cc);
        }
        __syncthreads();
        if (kb > qmax) continue;  // wave-uniform skip; barriers stay at loop top

        // S = Q K^T : 4 key-subtiles of 16, 4 k-steps each (independent chains)
        f32x4 s[4];
#pragma unroll
        for (int st = 0; st < 4; ++st) s[st] = zero;
#pragma unroll
        for (int kk = 0; kk < 4; ++kk) {
#pragma unroll
            for (int st = 0; st < 4; ++st) {
                bf16x8 b = *reinterpret_cast<const bf16x8*>(
                    &lK[(st * 16 + l16) * 136 + kk * 32 + quad * 8]);
                s[st] = __builtin_amdgcn_mfma_f32_16x16x32_bf16(aQ[kk], b, s[st], 0, 0, 0);
            }
        }

        // online softmax per row (rows = quad*4+r; key cols = st*16 + l16)
        int qg = qb + wave * 16 + quad * 4;
#pragma unroll
        for (int r = 0; r < 4; ++r) {
            int q = qg + r;
            float x[4];
#pragma unroll
            for (int st = 0; st < 4; ++st)
                x[st] = (kb + st * 16 + l16 <= q) ? s[st][r] * scl : -1e30f;
            float mx = fmaxf(fmaxf(x[0], x[1]), fmaxf(x[2], x[3]));
#pragma unroll
            for (int off = 1; off < 16; off <<= 1) mx = fmaxf(mx, __shfl_xor(mx, off));
            float mn = fmaxf(m_s[r], mx);
            float al = __expf(m_s[r] - mn);
            float p[4], rs = 0.f;
#pragma unroll
            for (int st = 0; st < 4; ++st) { p[st] = __expf(x[st] - mn); rs += p[st]; }
#pragma unroll
            for (int off = 1; off < 16; off <<= 1) rs += __shfl_xor(rs, off);
            m_s[r] = mn;
            l_s[r] = l_s[r] * al + rs;
            int row = quad * 4 + r;
#pragma unroll
            for (int st = 0; st < 4; ++st)
                lP[wave][row * 72 + st * 16 + l16] = f2bs(p[st]);
#pragma unroll
            for (int h = 0; h < 8; ++h) O[h][r] *= al;
        }

        // P (A-layout) @ V -> O over 8 hd-tiles x 2 key-chunks
#pragma unroll
        for (int kc = 0; kc < 2; ++kc) {
            bf16x8 pf = *reinterpret_cast<const bf16x8*>(
                &lP[wave][l16 * 72 + kc * 32 + quad * 8]);
#pragma unroll
            for (int h = 0; h < 8; ++h) {
                bf16x8 vf = *reinterpret_cast<const bf16x8*>(
                    &lVt[(h * 16 + l16) * 72 + kc * 32 + quad * 8]);
                O[h] = __builtin_amdgcn_mfma_f32_16x16x32_bf16(pf, vf, O[h], 0, 0, 0);
            }
        }
    }

    // write y[b*T+t][hh*128 + hd] bf16
    int b = bh >> 4, hh = bh & 15;
#pragma unroll
    for (int r = 0; r < 4; ++r) {
        int t = qb + wave * 16 + quad * 4 + r;
        float inv = 1.f / l_s[r];
#pragma unroll
        for (int h = 0; h < 8; ++h)
            y[(long)(b * T_ + t) * C_ + hh * HD_ + h * 16 + l16] = f2bs(O[h][r] * inv);
    }
}

extern "C" void kernel_launch(void* const* d_in, const int* in_sizes, int n_in,
                              void* d_out, int out_size, void* d_ws, size_t ws_size,
                              hipStream_t stream) {
    const float* x     = (const float*)d_in[0];
    // d_in[1] = causal mask, ignored (handled analytically)
    const float* Wqkv  = (const float*)d_in[2];
    const float* Wproj = (const float*)d_in[3];
    const float* bproj = (const float*)d_in[4];
    float* out = (float*)d_out;

    // workspace layout (bf16 elements); y aliases XB (XB dead after gemm1)
    unsigned short* XB     = (unsigned short*)d_ws;   // [4096][2048]  (later: y)
    unsigned short* WQKVT  = XB + 8388608;            // [6144][2048]
    unsigned short* WPROJT = WQKVT + 12582912;        // [2048][2048]
    unsigned short* QKV    = WPROJT + 4194304;        // [3][32][...]
    if (ws_size < 100663296) return;                  // 96 MB needed

    k_f2b<<<8192, 256, 0, stream>>>(x, XB, 8388608 / 4);
    k_transpose_f2b<<<dim3(6144 / 64, 2048 / 64), 256, 0, stream>>>(Wqkv, WQKVT, 2048, 6144);
    k_transpose_f2b<<<dim3(2048 / 64, 2048 / 64), 256, 0, stream>>>(Wproj, WPROJT, 2048, 2048);
    k_gemm<0><<<dim3(6144 / 128, 4096 / 128), 256, 0, stream>>>(XB, WQKVT, 4096, 6144, 2048,
                                                                QKV, nullptr, nullptr);
    k_attn<<<dim3(32, 32), 256, 0, stream>>>(QKV, XB);
    k_gemm<1><<<dim3(2048 / 128, 4096 / 128), 256, 0, stream>>>(XB, WPROJT, 4096, 2048, 2048,
                                                                nullptr, out, bproj);
}

// Round 3
// 431.427 us; speedup vs baseline: 1.2681x; 1.0136x over previous
//
#include <hip/hip_runtime.h>
#include <hip/hip_bf16.h>

// B=2, T=2048, C=2048, H=16, HD=128
#define B_  2
#define T_  2048
#define C_  2048
#define H_  16
#define HD_ 128

using bf16x8 = __attribute__((ext_vector_type(8))) __bf16;
using f32x4  = __attribute__((ext_vector_type(4))) float;

__device__ __forceinline__ unsigned short f2bs(float f) {
    __hip_bfloat16 h = __float2bfloat16(f);
    return __builtin_bit_cast(unsigned short, h);
}

// async global->LDS, 16B per lane; LDS dest = wave-uniform base + lane*16
__device__ __forceinline__ void gload_lds16(const unsigned short* g, unsigned short* l) {
    __builtin_amdgcn_global_load_lds(
        (const __attribute__((address_space(1))) unsigned int*)g,
        (__attribute__((address_space(3))) unsigned int*)l, 16, 0, 0);
}

// ---------------- convert fp32 -> bf16 (vectorized) ----------------
__global__ void k_f2b(const float* __restrict__ in, unsigned short* __restrict__ out, int n4) {
    int i = blockIdx.x * blockDim.x + threadIdx.x;
    if (i < n4) {
        float4 v = reinterpret_cast<const float4*>(in)[i];
        ushort4 o;
        o.x = f2bs(v.x); o.y = f2bs(v.y); o.z = f2bs(v.z); o.w = f2bs(v.w);
        reinterpret_cast<ushort4*>(out)[i] = o;
    }
}

// ---------------- transpose + convert: in [K][N] fp32 -> out [N][K] bf16 ----------------
__global__ __launch_bounds__(256) void k_transpose_f2b(const float* __restrict__ in,
                                                       unsigned short* __restrict__ out,
                                                       int K, int N) {
    __shared__ unsigned short t[64][65];
    int k0 = blockIdx.y * 64, n0 = blockIdx.x * 64;
    int tid = threadIdx.x;
#pragma unroll
    for (int p = 0; p < 4; ++p) {
        int idx = p * 256 + tid;
        int r = idx >> 4, c = (idx & 15) << 2;
        float4 v = *reinterpret_cast<const float4*>(in + (long)(k0 + r) * N + n0 + c);
        t[r][c] = f2bs(v.x); t[r][c + 1] = f2bs(v.y);
        t[r][c + 2] = f2bs(v.z); t[r][c + 3] = f2bs(v.w);
    }
    __syncthreads();
#pragma unroll
    for (int p = 0; p < 4; ++p) {
        int idx = p * 256 + tid;
        int r = idx >> 4, c = (idx & 15) << 2;
        ushort4 o;
        o.x = t[c][r]; o.y = t[c + 1][r]; o.z = t[c + 2][r]; o.w = t[c + 3][r];
        *reinterpret_cast<ushort4*>(out + (long)(n0 + r) * K + k0 + c) = o;
    }
}

// ---------------- GEMM: A[M][K] bf16 x Bt[N][K] bf16 -> epilogue per MODE ----------------
// m97 structure: 128x128 tile, BK=32, global_load_lds width-16 staging, unpadded LDS.
// MODE 0: write qkv, Q/K as [bh][T][HD], V transposed as [bh][HD][T].
// MODE 1: out fp32 [M][N] + bias.
template <int MODE>
__global__ __launch_bounds__(256, 2) void k_gemm(const unsigned short* __restrict__ A,
                                                 const unsigned short* __restrict__ Bt,
                                                 int M, int N, int K,
                                                 unsigned short* __restrict__ qkv,
                                                 float* __restrict__ out,
                                                 const float* __restrict__ bias) {
    // unpadded [128][32] — required: global_load_lds scatters lane*16B contiguously.
    // fragment reads at 64B row stride are conflict-free (8 lanes per 4-bank group, b128 min).
    __shared__ __align__(16) unsigned short lA[128 * 32];
    __shared__ __align__(16) unsigned short lB[128 * 32];

    int tid = threadIdx.x;
    int wave = tid >> 6, lane = tid & 63;
    int quad = lane >> 4, l16 = lane & 15;
    int wr = (wave >> 1) * 64, wc = (wave & 1) * 64;
    int m0 = blockIdx.y * 128, n0 = blockIdx.x * 128;

    // staging: wave w, part p covers rows [w*32+p*16, +16), lane -> row w*32+p*16+lane/4,
    // col (lane&3)*8; LDS uniform base = element (w*1024 + p*512)
    int lrow = lane >> 2;          // 0..15
    int lcol = (lane & 3) << 3;    // 0,8,16,24
    const unsigned short* gA0 = A + (long)(m0 + wave * 32 + lrow) * K + lcol;
    const unsigned short* gA1 = A + (long)(m0 + wave * 32 + 16 + lrow) * K + lcol;
    const unsigned short* gB0 = Bt + (long)(n0 + wave * 32 + lrow) * K + lcol;
    const unsigned short* gB1 = Bt + (long)(n0 + wave * 32 + 16 + lrow) * K + lcol;
    unsigned short* lA0 = &lA[wave * 1024];
    unsigned short* lA1 = &lA[wave * 1024 + 512];
    unsigned short* lB0 = &lB[wave * 1024];
    unsigned short* lB1 = &lB[wave * 1024 + 512];

    f32x4 zero = {0.f, 0.f, 0.f, 0.f};
    f32x4 acc[4][4];
#pragma unroll
    for (int i = 0; i < 4; ++i)
#pragma unroll
        for (int j = 0; j < 4; ++j) acc[i][j] = zero;

    for (int k0 = 0; k0 < K; k0 += 32) {
        __syncthreads();
        gload_lds16(gA0 + k0, lA0);
        gload_lds16(gA1 + k0, lA1);
        gload_lds16(gB0 + k0, lB0);
        gload_lds16(gB1 + k0, lB1);
        __syncthreads();  // compiler emits s_waitcnt vmcnt(0) before s_barrier
        bf16x8 af[4], bfr[4];
#pragma unroll
        for (int i = 0; i < 4; ++i)
            af[i] = *reinterpret_cast<const bf16x8*>(&lA[(wr + i * 16 + l16) * 32 + quad * 8]);
#pragma unroll
        for (int j = 0; j < 4; ++j)
            bfr[j] = *reinterpret_cast<const bf16x8*>(&lB[(wc + j * 16 + l16) * 32 + quad * 8]);
#pragma unroll
        for (int i = 0; i < 4; ++i)
#pragma unroll
            for (int j = 0; j < 4; ++j)
                acc[i][j] = __builtin_amdgcn_mfma_f32_16x16x32_bf16(af[i], bfr[j], acc[i][j], 0, 0, 0);
    }

#pragma unroll
    for (int i = 0; i < 4; ++i) {
#pragma unroll
        for (int j = 0; j < 4; ++j) {
#pragma unroll
            for (int r = 0; r < 4; ++r) {
                int m = m0 + wr + i * 16 + quad * 4 + r;
                int n = n0 + wc + j * 16 + l16;
                float v = acc[i][j][r];
                if (MODE == 0) {
                    int s = n >> 11, col = n & 2047;
                    int h = col >> 7, hd = col & 127;
                    int b = m >> 11, t = m & 2047;
                    long base = (long)s * (B_ * H_ * T_ * HD_);
                    if (s == 2)  // V stored transposed: [bh][HD][T]
                        qkv[base + ((long)(b * H_ + h) * HD_ + hd) * T_ + t] = f2bs(v);
                    else
                        qkv[base + ((long)(b * H_ + h) * T_ + t) * HD_ + hd] = f2bs(v);
                } else {
                    out[(long)m * N + n] = v + bias[n];
                }
            }
        }
    }
}

// ---------------- flash attention ----------------
// qkv: Q,K [bh][T][HD], V [bh][HD][T] (pre-transposed), all bf16 -> y [B*T][C] bf16
// block: 4 waves, 64 q-rows (16/wave), kv-step 64. Grid (bh=32, qtile=32), longest-first.
__global__ __launch_bounds__(256, 3) void k_attn(const unsigned short* __restrict__ qkv,
                                                 unsigned short* __restrict__ y) {
    __shared__ __align__(16) unsigned short lK[64 * 136];    // [key][hd], stride 136
    __shared__ __align__(16) unsigned short lVt[128 * 72];   // [hd][key], stride 72
    __shared__ __align__(16) unsigned short lP[4][16 * 72];  // per-wave P [qrow][key]

    int tid = threadIdx.x;
    int wave = tid >> 6, lane = tid & 63;
    int quad = lane >> 4, l16 = lane & 15;
    int bh = blockIdx.x;                          // 0..31
    int qb = ((int)gridDim.y - 1 - (int)blockIdx.y) * 64;  // heavy tiles dispatch first

    const unsigned short* Qh = qkv + (long)bh * (T_ * HD_);
    const unsigned short* Kh = qkv + (long)(B_ * H_) * T_ * HD_ + (long)bh * (T_ * HD_);
    const unsigned short* Vt = qkv + 2L * (B_ * H_) * T_ * HD_ + (long)bh * (HD_ * T_);

    // preload this wave's 16 Q rows as A-fragments (A[m=l16][k=quad*8+j], 4 k-steps)
    bf16x8 aQ[4];
    int qrow = qb + wave * 16 + l16;
#pragma unroll
    for (int kk = 0; kk < 4; ++kk)
        aQ[kk] = *reinterpret_cast<const bf16x8*>(Qh + (long)qrow * HD_ + kk * 32 + quad * 8);

    float m_s[4], l_s[4];
    f32x4 O[8];
    f32x4 zero = {0.f, 0.f, 0.f, 0.f};
#pragma unroll
    for (int r = 0; r < 4; ++r) { m_s[r] = -1e30f; l_s[r] = 0.f; }
#pragma unroll
    for (int h = 0; h < 8; ++h) O[h] = zero;

    int qmax = qb + wave * 16 + 15;
    const float scl = 0.08838834764831845f;  // 1/sqrt(128)

    for (int kb = 0; kb < qb + 64; kb += 64) {
        __syncthreads();
        // stage K tile [64 keys][128 hd] -> lK (coalesced int4, b128 LDS writes)
#pragma unroll
        for (int p = 0; p < 4; ++p) {
            int id = p * 256 + tid;
            int r = id >> 4, cc = (id & 15) << 3;
            *reinterpret_cast<int4*>(&lK[r * 136 + cc]) =
                *reinterpret_cast<const int4*>(Kh + (long)(kb + r) * HD_ + cc);
        }
        // stage Vt tile [128 hd][64 keys] -> lVt (already transposed in global)
#pragma unroll
        for (int p = 0; p < 4; ++p) {
            int id = p * 256 + tid;
            int r = id >> 3, cc = (id & 7) << 3;
            *reinterpret_cast<int4*>(&lVt[r * 72 + cc]) =
                *reinterpret_cast<const int4*>(Vt + (long)r * T_ + kb + cc);
        }
        __syncthreads();
        if (kb > qmax) continue;  // wave-uniform skip; barriers stay at loop top

        // S = Q K^T : 4 key-subtiles of 16, 4 k-steps each (independent chains)
        f32x4 s[4];
#pragma unroll
        for (int st = 0; st < 4; ++st) s[st] = zero;
#pragma unroll
        for (int kk = 0; kk < 4; ++kk) {
#pragma unroll
            for (int st = 0; st < 4; ++st) {
                bf16x8 b = *reinterpret_cast<const bf16x8*>(
                    &lK[(st * 16 + l16) * 136 + kk * 32 + quad * 8]);
                s[st] = __builtin_amdgcn_mfma_f32_16x16x32_bf16(aQ[kk], b, s[st], 0, 0, 0);
            }
        }

        // online softmax per row (rows = quad*4+r; key cols = st*16 + l16)
        int qg = qb + wave * 16 + quad * 4;
#pragma unroll
        for (int r = 0; r < 4; ++r) {
            int q = qg + r;
            float x[4];
#pragma unroll
            for (int st = 0; st < 4; ++st)
                x[st] = (kb + st * 16 + l16 <= q) ? s[st][r] * scl : -1e30f;
            float mx = fmaxf(fmaxf(x[0], x[1]), fmaxf(x[2], x[3]));
#pragma unroll
            for (int off = 1; off < 16; off <<= 1) mx = fmaxf(mx, __shfl_xor(mx, off));
            float mn = fmaxf(m_s[r], mx);
            float al = __expf(m_s[r] - mn);
            float p[4], rs = 0.f;
#pragma unroll
            for (int st = 0; st < 4; ++st) { p[st] = __expf(x[st] - mn); rs += p[st]; }
#pragma unroll
            for (int off = 1; off < 16; off <<= 1) rs += __shfl_xor(rs, off);
            m_s[r] = mn;
            l_s[r] = l_s[r] * al + rs;
            int row = quad * 4 + r;
#pragma unroll
            for (int st = 0; st < 4; ++st)
                lP[wave][row * 72 + st * 16 + l16] = f2bs(p[st]);
#pragma unroll
            for (int h = 0; h < 8; ++h) O[h][r] *= al;
        }

        // P (A-layout) @ V -> O over 8 hd-tiles x 2 key-chunks
#pragma unroll
        for (int kc = 0; kc < 2; ++kc) {
            bf16x8 pf = *reinterpret_cast<const bf16x8*>(
                &lP[wave][l16 * 72 + kc * 32 + quad * 8]);
#pragma unroll
            for (int h = 0; h < 8; ++h) {
                bf16x8 vf = *reinterpret_cast<const bf16x8*>(
                    &lVt[(h * 16 + l16) * 72 + kc * 32 + quad * 8]);
                O[h] = __builtin_amdgcn_mfma_f32_16x16x32_bf16(pf, vf, O[h], 0, 0, 0);
            }
        }
    }

    // write y[b*T+t][hh*128 + hd] bf16
    int b = bh >> 4, hh = bh & 15;
#pragma unroll
    for (int r = 0; r < 4; ++r) {
        int t = qb + wave * 16 + quad * 4 + r;
        float inv = 1.f / l_s[r];
#pragma unroll
        for (int h = 0; h < 8; ++h)
            y[(long)(b * T_ + t) * C_ + hh * HD_ + h * 16 + l16] = f2bs(O[h][r] * inv);
    }
}

extern "C" void kernel_launch(void* const* d_in, const int* in_sizes, int n_in,
                              void* d_out, int out_size, void* d_ws, size_t ws_size,
                              hipStream_t stream) {
    const float* x     = (const float*)d_in[0];
    // d_in[1] = causal mask, ignored (handled analytically)
    const float* Wqkv  = (const float*)d_in[2];
    const float* Wproj = (const float*)d_in[3];
    const float* bproj = (const float*)d_in[4];
    float* out = (float*)d_out;

    // workspace layout (bf16 elements); y aliases XB (XB dead after gemm1)
    unsigned short* XB     = (unsigned short*)d_ws;   // [4096][2048]  (later: y)
    unsigned short* WQKVT  = XB + 8388608;            // [6144][2048]
    unsigned short* WPROJT = WQKVT + 12582912;        // [2048][2048]
    unsigned short* QKV    = WPROJT + 4194304;        // [3][32][...]
    if (ws_size < 100663296) return;                  // 96 MB needed

    k_f2b<<<8192, 256, 0, stream>>>(x, XB, 8388608 / 4);
    k_transpose_f2b<<<dim3(6144 / 64, 2048 / 64), 256, 0, stream>>>(Wqkv, WQKVT, 2048, 6144);
    k_transpose_f2b<<<dim3(2048 / 64, 2048 / 64), 256, 0, stream>>>(Wproj, WPROJT, 2048, 2048);
    k_gemm<0><<<dim3(6144 / 128, 4096 / 128), 256, 0, stream>>>(XB, WQKVT, 4096, 6144, 2048,
                                                                QKV, nullptr, nullptr);
    k_attn<<<dim3(32, 32), 256, 0, stream>>>(QKV, XB);
    k_gemm<1><<<dim3(2048 / 128, 4096 / 128), 256, 0, stream>>>(XB, WPROJT, 4096, 2048, 2048,
                                                                nullptr, out, bproj);
}

// Round 4
// 404.943 us; speedup vs baseline: 1.3510x; 1.0654x over previous
//
#include <hip/hip_runtime.h>
#include <hip/hip_bf16.h>

// B=2, T=2048, C=2048, H=16, HD=128
#define B_  2
#define T_  2048
#define C_  2048
#define H_  16
#define HD_ 128

using bf16x8 = __attribute__((ext_vector_type(8))) __bf16;
using f32x4  = __attribute__((ext_vector_type(4))) float;

__device__ __forceinline__ unsigned short f2bs(float f) {
    __hip_bfloat16 h = __float2bfloat16(f);
    return __builtin_bit_cast(unsigned short, h);
}

// async global->LDS, 16B per lane; LDS dest = wave-uniform base + lane*16
__device__ __forceinline__ void gload_lds16(const unsigned short* g, unsigned short* l) {
    __builtin_amdgcn_global_load_lds(
        (const __attribute__((address_space(1))) unsigned int*)g,
        (__attribute__((address_space(3))) unsigned int*)l, 16, 0, 0);
}

// ---------------- merged prep: fp32->bf16 convert + 2 weight transposes ----------------
// blocks [0,8192): x convert; [8192,11264): Wqkv^T; [11264,12288): Wproj^T
__global__ __launch_bounds__(256) void k_prep(const float* __restrict__ x,
                                              unsigned short* __restrict__ XB,
                                              const float* __restrict__ Wqkv,
                                              unsigned short* __restrict__ WQKVT,
                                              const float* __restrict__ Wproj,
                                              unsigned short* __restrict__ WPROJT) {
    __shared__ unsigned short t[64][65];
    int blk = blockIdx.x;
    int tid = threadIdx.x;
    if (blk < 8192) {
        int i = blk * 256 + tid;
        float4 v = reinterpret_cast<const float4*>(x)[i];
        ushort4 o;
        o.x = f2bs(v.x); o.y = f2bs(v.y); o.z = f2bs(v.z); o.w = f2bs(v.w);
        reinterpret_cast<ushort4*>(XB)[i] = o;
        return;
    }
    const float* in;
    unsigned short* out;
    int K = 2048, N, bx, by;
    if (blk < 11264) {
        in = Wqkv; out = WQKVT; N = 6144;
        bx = (blk - 8192) % 96; by = (blk - 8192) / 96;
    } else {
        in = Wproj; out = WPROJT; N = 2048;
        bx = (blk - 11264) % 32; by = (blk - 11264) / 32;
    }
    int k0 = by * 64, n0 = bx * 64;
#pragma unroll
    for (int p = 0; p < 4; ++p) {
        int idx = p * 256 + tid;
        int r = idx >> 4, c = (idx & 15) << 2;
        float4 v = *reinterpret_cast<const float4*>(in + (long)(k0 + r) * N + n0 + c);
        t[r][c] = f2bs(v.x); t[r][c + 1] = f2bs(v.y);
        t[r][c + 2] = f2bs(v.z); t[r][c + 3] = f2bs(v.w);
    }
    __syncthreads();
#pragma unroll
    for (int p = 0; p < 4; ++p) {
        int idx = p * 256 + tid;
        int r = idx >> 4, c = (idx & 15) << 2;
        ushort4 o;
        o.x = t[c][r]; o.y = t[c + 1][r]; o.z = t[c + 2][r]; o.w = t[c + 3][r];
        *reinterpret_cast<ushort4*>(out + (long)(n0 + r) * K + k0 + c) = o;
    }
}

// ---------------- GEMM: A[M][K] bf16 x Bt[N][K] bf16 -> epilogue per MODE ----------------
// 128x128 tile, BK=64 as two BK=32 sub-buffers (keeps m97's conflict-free unpadded
// [128][32] layout + global_load_lds staging, halves barrier count: 32 MFMA/barrier).
// MODE 0: write qkv, Q/K as [bh][T][HD], V transposed as [bh][HD][T].
// MODE 1: out fp32 [M][N] + bias.
template <int MODE>
__global__ __launch_bounds__(256, 2) void k_gemm(const unsigned short* __restrict__ A,
                                                 const unsigned short* __restrict__ Bt,
                                                 int M, int N, int K,
                                                 unsigned short* __restrict__ qkv,
                                                 float* __restrict__ out,
                                                 const float* __restrict__ bias) {
    __shared__ __align__(16) unsigned short lA[2][128 * 32];
    __shared__ __align__(16) unsigned short lB[2][128 * 32];

    int tid = threadIdx.x;
    int wave = tid >> 6, lane = tid & 63;
    int quad = lane >> 4, l16 = lane & 15;
    int wr = (wave >> 1) * 64, wc = (wave & 1) * 64;
    int m0 = blockIdx.y * 128, n0 = blockIdx.x * 128;

    // staging: wave w, part p covers rows [w*32+p*16, +16): lane -> row w*32+p*16+lane/4,
    // col (lane&3)*8; LDS uniform base = element (w*1024 + p*512)
    int lrow = lane >> 2;          // 0..15
    int lcol = (lane & 3) << 3;    // 0,8,16,24
    const unsigned short* gA0 = A + (long)(m0 + wave * 32 + lrow) * K + lcol;
    const unsigned short* gA1 = A + (long)(m0 + wave * 32 + 16 + lrow) * K + lcol;
    const unsigned short* gB0 = Bt + (long)(n0 + wave * 32 + lrow) * K + lcol;
    const unsigned short* gB1 = Bt + (long)(n0 + wave * 32 + 16 + lrow) * K + lcol;
    int lofs0 = wave * 1024, lofs1 = wave * 1024 + 512;

    f32x4 zero = {0.f, 0.f, 0.f, 0.f};
    f32x4 acc[4][4];
#pragma unroll
    for (int i = 0; i < 4; ++i)
#pragma unroll
        for (int j = 0; j < 4; ++j) acc[i][j] = zero;

    for (int k0 = 0; k0 < K; k0 += 64) {
        __syncthreads();
#pragma unroll
        for (int h = 0; h < 2; ++h) {
            int kk = k0 + h * 32;
            gload_lds16(gA0 + kk, &lA[h][lofs0]);
            gload_lds16(gA1 + kk, &lA[h][lofs1]);
            gload_lds16(gB0 + kk, &lB[h][lofs0]);
            gload_lds16(gB1 + kk, &lB[h][lofs1]);
        }
        __syncthreads();  // single vmcnt(0) drain per 32 MFMA now
#pragma unroll
        for (int h = 0; h < 2; ++h) {
            bf16x8 af[4], bfr[4];
#pragma unroll
            for (int i = 0; i < 4; ++i)
                af[i] = *reinterpret_cast<const bf16x8*>(&lA[h][(wr + i * 16 + l16) * 32 + quad * 8]);
#pragma unroll
            for (int j = 0; j < 4; ++j)
                bfr[j] = *reinterpret_cast<const bf16x8*>(&lB[h][(wc + j * 16 + l16) * 32 + quad * 8]);
#pragma unroll
            for (int i = 0; i < 4; ++i)
#pragma unroll
                for (int j = 0; j < 4; ++j)
                    acc[i][j] = __builtin_amdgcn_mfma_f32_16x16x32_bf16(af[i], bfr[j], acc[i][j], 0, 0, 0);
        }
    }

#pragma unroll
    for (int i = 0; i < 4; ++i) {
#pragma unroll
        for (int j = 0; j < 4; ++j) {
#pragma unroll
            for (int r = 0; r < 4; ++r) {
                int m = m0 + wr + i * 16 + quad * 4 + r;
                int n = n0 + wc + j * 16 + l16;
                float v = acc[i][j][r];
                if (MODE == 0) {
                    int s = n >> 11, col = n & 2047;
                    int h = col >> 7, hd = col & 127;
                    int b = m >> 11, t = m & 2047;
                    long base = (long)s * (B_ * H_ * T_ * HD_);
                    if (s == 2)  // V stored transposed: [bh][HD][T]
                        qkv[base + ((long)(b * H_ + h) * HD_ + hd) * T_ + t] = f2bs(v);
                    else
                        qkv[base + ((long)(b * H_ + h) * T_ + t) * HD_ + hd] = f2bs(v);
                } else {
                    out[(long)m * N + n] = v + bias[n];
                }
            }
        }
    }
}

// ---------------- flash attention ----------------
// qkv: Q,K [bh][T][HD], V [bh][HD][T] (pre-transposed), all bf16 -> y [B*T][C] bf16
// block: 4 waves, 64 q-rows (16/wave), kv-step 64. Grid (bh=32, qtile=32), longest-first.
__global__ __launch_bounds__(256, 3) void k_attn(const unsigned short* __restrict__ qkv,
                                                 unsigned short* __restrict__ y) {
    __shared__ __align__(16) unsigned short lK[64 * 136];    // [key][hd], stride 136
    __shared__ __align__(16) unsigned short lVt[128 * 72];   // [hd][key], stride 72
    __shared__ __align__(16) unsigned short lP[4][16 * 72];  // per-wave P [qrow][key]

    int tid = threadIdx.x;
    int wave = tid >> 6, lane = tid & 63;
    int quad = lane >> 4, l16 = lane & 15;
    int bh = blockIdx.x;                          // 0..31
    int qb = ((int)gridDim.y - 1 - (int)blockIdx.y) * 64;  // heavy tiles dispatch first

    const unsigned short* Qh = qkv + (long)bh * (T_ * HD_);
    const unsigned short* Kh = qkv + (long)(B_ * H_) * T_ * HD_ + (long)bh * (T_ * HD_);
    const unsigned short* Vt = qkv + 2L * (B_ * H_) * T_ * HD_ + (long)bh * (HD_ * T_);

    // preload this wave's 16 Q rows as A-fragments (A[m=l16][k=quad*8+j], 4 k-steps)
    bf16x8 aQ[4];
    int qrow = qb + wave * 16 + l16;
#pragma unroll
    for (int kk = 0; kk < 4; ++kk)
        aQ[kk] = *reinterpret_cast<const bf16x8*>(Qh + (long)qrow * HD_ + kk * 32 + quad * 8);

    float m_s[4], l_s[4];
    f32x4 O[8];
    f32x4 zero = {0.f, 0.f, 0.f, 0.f};
#pragma unroll
    for (int r = 0; r < 4; ++r) { m_s[r] = -1e30f; l_s[r] = 0.f; }
#pragma unroll
    for (int h = 0; h < 8; ++h) O[h] = zero;

    int qmax = qb + wave * 16 + 15;
    const float scl = 0.08838834764831845f;  // 1/sqrt(128)

    for (int kb = 0; kb < qb + 64; kb += 64) {
        __syncthreads();
        // stage K tile [64 keys][128 hd] -> lK (coalesced int4, b128 LDS writes)
#pragma unroll
        for (int p = 0; p < 4; ++p) {
            int id = p * 256 + tid;
            int r = id >> 4, cc = (id & 15) << 3;
            *reinterpret_cast<int4*>(&lK[r * 136 + cc]) =
                *reinterpret_cast<const int4*>(Kh + (long)(kb + r) * HD_ + cc);
        }
        // stage Vt tile [128 hd][64 keys] -> lVt (already transposed in global)
#pragma unroll
        for (int p = 0; p < 4; ++p) {
            int id = p * 256 + tid;
            int r = id >> 3, cc = (id & 7) << 3;
            *reinterpret_cast<int4*>(&lVt[r * 72 + cc]) =
                *reinterpret_cast<const int4*>(Vt + (long)r * T_ + kb + cc);
        }
        __syncthreads();
        if (kb > qmax) continue;  // wave-uniform skip; barriers stay at loop top

        // S = Q K^T : 4 key-subtiles of 16, 4 k-steps each (independent chains)
        f32x4 s[4];
#pragma unroll
        for (int st = 0; st < 4; ++st) s[st] = zero;
#pragma unroll
        for (int kk = 0; kk < 4; ++kk) {
#pragma unroll
            for (int st = 0; st < 4; ++st) {
                bf16x8 b = *reinterpret_cast<const bf16x8*>(
                    &lK[(st * 16 + l16) * 136 + kk * 32 + quad * 8]);
                s[st] = __builtin_amdgcn_mfma_f32_16x16x32_bf16(aQ[kk], b, s[st], 0, 0, 0);
            }
        }

        // online softmax per row (rows = quad*4+r; key cols = st*16 + l16)
        int qg = qb + wave * 16 + quad * 4;
#pragma unroll
        for (int r = 0; r < 4; ++r) {
            int q = qg + r;
            float x[4];
#pragma unroll
            for (int st = 0; st < 4; ++st)
                x[st] = (kb + st * 16 + l16 <= q) ? s[st][r] * scl : -1e30f;
            float mx = fmaxf(fmaxf(x[0], x[1]), fmaxf(x[2], x[3]));
#pragma unroll
            for (int off = 1; off < 16; off <<= 1) mx = fmaxf(mx, __shfl_xor(mx, off));
            float mn = fmaxf(m_s[r], mx);
            float al = __expf(m_s[r] - mn);
            float p[4], rs = 0.f;
#pragma unroll
            for (int st = 0; st < 4; ++st) { p[st] = __expf(x[st] - mn); rs += p[st]; }
#pragma unroll
            for (int off = 1; off < 16; off <<= 1) rs += __shfl_xor(rs, off);
            m_s[r] = mn;
            l_s[r] = l_s[r] * al + rs;
            int row = quad * 4 + r;
#pragma unroll
            for (int st = 0; st < 4; ++st)
                lP[wave][row * 72 + st * 16 + l16] = f2bs(p[st]);
#pragma unroll
            for (int h = 0; h < 8; ++h) O[h][r] *= al;
        }

        // P (A-layout) @ V -> O over 8 hd-tiles x 2 key-chunks
#pragma unroll
        for (int kc = 0; kc < 2; ++kc) {
            bf16x8 pf = *reinterpret_cast<const bf16x8*>(
                &lP[wave][l16 * 72 + kc * 32 + quad * 8]);
#pragma unroll
            for (int h = 0; h < 8; ++h) {
                bf16x8 vf = *reinterpret_cast<const bf16x8*>(
                    &lVt[(h * 16 + l16) * 72 + kc * 32 + quad * 8]);
                O[h] = __builtin_amdgcn_mfma_f32_16x16x32_bf16(pf, vf, O[h], 0, 0, 0);
            }
        }
    }

    // write y[b*T+t][hh*128 + hd] bf16
    int b = bh >> 4, hh = bh & 15;
#pragma unroll
    for (int r = 0; r < 4; ++r) {
        int t = qb + wave * 16 + quad * 4 + r;
        float inv = 1.f / l_s[r];
#pragma unroll
        for (int h = 0; h < 8; ++h)
            y[(long)(b * T_ + t) * C_ + hh * HD_ + h * 16 + l16] = f2bs(O[h][r] * inv);
    }
}

extern "C" void kernel_launch(void* const* d_in, const int* in_sizes, int n_in,
                              void* d_out, int out_size, void* d_ws, size_t ws_size,
                              hipStream_t stream) {
    const float* x     = (const float*)d_in[0];
    // d_in[1] = causal mask, ignored (handled analytically)
    const float* Wqkv  = (const float*)d_in[2];
    const float* Wproj = (const float*)d_in[3];
    const float* bproj = (const float*)d_in[4];
    float* out = (float*)d_out;

    // workspace layout (bf16 elements); y aliases XB (XB dead after gemm1)
    unsigned short* XB     = (unsigned short*)d_ws;   // [4096][2048]  (later: y)
    unsigned short* WQKVT  = XB + 8388608;            // [6144][2048]
    unsigned short* WPROJT = WQKVT + 12582912;        // [2048][2048]
    unsigned short* QKV    = WPROJT + 4194304;        // [3][32][...]
    if (ws_size < 100663296) return;                  // 96 MB needed

    k_prep<<<12288, 256, 0, stream>>>(x, XB, Wqkv, WQKVT, Wproj, WPROJT);
    k_gemm<0><<<dim3(6144 / 128, 4096 / 128), 256, 0, stream>>>(XB, WQKVT, 4096, 6144, 2048,
                                                                QKV, nullptr, nullptr);
    k_attn<<<dim3(32, 32), 256, 0, stream>>>(QKV, XB);
    k_gemm<1><<<dim3(2048 / 128, 4096 / 128), 256, 0, stream>>>(XB, WPROJT, 4096, 2048, 2048,
                                                                nullptr, out, bproj);
}